// Round 1
// baseline (810.359 us; speedup 1.0000x reference)
//
#include <hip/hip_runtime.h>
#include <math.h>

// Problem constants (from reference)
#define NB   4
#define NC   4
#define NF   257
#define NFRM 2000
#define PLANE (NB*NC*NF*NFRM)   // 8,224,000
#define NFCH  4                 // frequency chunks for r-partials
#define FPERC 65                // ceil(257/4)
#define KU_THREADS 512
#define KU_K 4                  // frames per thread (4*512 >= 2000)

__device__ __forceinline__ float2 cmulf(float2 a, float2 b) {
  return make_float2(a.x*b.x - a.y*b.y, a.x*b.y + a.y*b.x);
}

__global__ __launch_bounds__(64)
void k_zero(float* __restrict__ gpart) {
  if (threadIdx.x < 48) gpart[threadIdx.x] = 0.f;
}

// r-pass: partial[bc][fc][n] = sum over f-chunk of |X[b,c,f,n]|^2
// and gpart[bc] += sum over (f,n) of |X|^2 (one atomic per block)
__global__ __launch_bounds__(256)
void k_r(const float* __restrict__ Xr, const float* __restrict__ Xi,
         float* __restrict__ partial, float* __restrict__ gpart)
{
  const int tid = threadIdx.x;
  const int n   = blockIdx.x*256 + tid;
  const int fc  = blockIdx.y;
  const int bc  = blockIdx.z;          // b*4+c
  float s = 0.f;
  if (n < NFRM) {
    const int f0 = fc*FPERC;
    const int f1 = (f0+FPERC < NF) ? (f0+FPERC) : NF;
    int idx = (bc*NF + f0)*NFRM + n;
    for (int f=f0; f<f1; ++f) {
      float a = Xr[idx], b2 = Xi[idx];
      s += a*a + b2*b2;
      idx += NFRM;
    }
    partial[(bc*NFCH + fc)*NFRM + n] = s;
  }
  float t = s;
  #pragma unroll
  for (int o=32;o;o>>=1) t += __shfl_down(t, o);
  __shared__ float wred[4];
  const int lane = tid & 63, wid = tid >> 6;
  if (lane == 0) wred[wid] = t;
  __syncthreads();
  if (tid == 0) atomicAdd(&gpart[bc], wred[0]+wred[1]+wred[2]+wred[3]);
}

// Per-(b,f) update kernel: rescale, 4 type-1 + 8 type-2 ISS sweeps in LDS.
// LAST: fold projection_back (4x4 complex solve + scale) and write output planes in place.
template<bool FIRST, bool LAST>
__global__ __launch_bounds__(KU_THREADS)
void k_u(const float* Xsr, const float* Xsi,                 // current X source planes
         const float* __restrict__ Xor_, const float* __restrict__ Xoi_, // ORIGINAL input (for taps)
         float* Xdr, float* Xdi,                             // X dest planes (may alias source)
         const float* __restrict__ partial,
         const float* __restrict__ gpart,
         float2* __restrict__ Wg)
{
  __shared__ float2 Xc[NC][NFRM];   // 64,000 B
  __shared__ float2 Wl[NC][NC];
  __shared__ float wpart[8][12];
  __shared__ float vred[12];
  __shared__ float2 avec[NC];

  const int tid = threadIdx.x;
  const int f = blockIdx.x;
  const int b = blockIdx.y;
  const float norm = 1.0f/(float)NFRM;

  // g (per-channel gain) and 1/sqrt(g)
  float g[NC], igs[NC];
  #pragma unroll
  for (int c=0;c<NC;c++) {
    float m = gpart[b*NC+c] * (1.0f/(float)(NF*NFRM));
    g[c] = fmaxf(m, 1e-3f);
    igs[c] = 1.0f/sqrtf(g[c]);
  }

  // load + rescale X into LDS
  #pragma unroll
  for (int c=0;c<NC;c++) {
    const int rb = ((b*NC+c)*NF + f)*NFRM;
    #pragma unroll
    for (int k=0;k<KU_K;k++) {
      int n = tid + k*KU_THREADS;
      if (n < NFRM)
        Xc[c][n] = make_float2(Xsr[rb+n]*igs[c], Xsi[rb+n]*igs[c]);
    }
  }
  // weights = w0[b,c,n] * g[c]   (w0 from pre-scale X via r-partials)
  float w0g[NC][KU_K];
  #pragma unroll
  for (int k=0;k<KU_K;k++) {
    int n = tid + k*KU_THREADS;
    #pragma unroll
    for (int c=0;c<NC;c++) {
      float w = 0.f;
      if (n < NFRM) {
        const float* pp = partial + (b*NC+c)*NFCH*NFRM + n;
        float r = 0.f;
        #pragma unroll
        for (int ch=0; ch<NFCH; ch++) r += pp[ch*NFRM];
        w = 1.0f / fmaxf(2.0f*sqrtf(r), 1e-5f);
      }
      w0g[c][k] = w * g[c];
    }
  }
  // W load/init + rescale
  if (tid < 16) {
    const int c = tid>>2, d = tid&3;
    float2 w;
    if (FIRST) w = make_float2((c==d)?1.f:0.f, 0.f);
    else       w = Wg[(b*NF+f)*16 + tid];
    Wl[c][d] = make_float2(w.x*igs[c], w.y*igs[c]);
  }
  __syncthreads();

  // ---------- type-1 sweeps ----------
  for (int s=0;s<NC;s++) {
    float acc[12];
    #pragma unroll
    for (int i=0;i<12;i++) acc[i] = 0.f;
    float2 xs_c[KU_K];
    #pragma unroll
    for (int k=0;k<KU_K;k++) {
      int n = tid + k*KU_THREADS;
      if (n < NFRM) {
        float2 xs = Xc[s][n];
        xs_c[k] = xs;
        float m = xs.x*xs.x + xs.y*xs.y;
        #pragma unroll
        for (int c=0;c<NC;c++) {
          float2 xc = Xc[c][n];
          float w = w0g[c][k];
          acc[c]   += w*(xc.x*xs.x + xc.y*xs.y);   // Re  X[c]*conj(Xs)
          acc[4+c] += w*(xc.y*xs.x - xc.x*xs.y);   // Im
          acc[8+c] += w*m;                         // denom
        }
      }
    }
    #pragma unroll
    for (int o=32;o;o>>=1) {
      #pragma unroll
      for (int i=0;i<12;i++) acc[i] += __shfl_down(acc[i], o);
    }
    {
      const int lane = tid & 63, wid = tid >> 6;
      if (lane == 0) {
        #pragma unroll
        for (int i=0;i<12;i++) wpart[wid][i] = acc[i];
      }
    }
    __syncthreads();
    if (tid < 12) {
      float t = 0.f;
      #pragma unroll
      for (int w=0;w<8;w++) t += wpart[w][tid];
      vred[tid] = t;
    }
    __syncthreads();
    float2 v[NC];
    #pragma unroll
    for (int c=0;c<NC;c++) {
      float dn = fmaxf(vred[8+c]*norm, 1e-3f);
      v[c] = make_float2(vred[c]*norm/dn, vred[4+c]*norm/dn);
    }
    v[s] = make_float2(1.0f - 1.0f/sqrtf(fmaxf(vred[8+s]*norm, 1e-3f)), 0.f);
    // X update (each thread owns its frames; cached xs is the pre-update value)
    #pragma unroll
    for (int k=0;k<KU_K;k++) {
      int n = tid + k*KU_THREADS;
      if (n < NFRM) {
        float2 xs = xs_c[k];
        #pragma unroll
        for (int c=0;c<NC;c++) {
          float2 xv = Xc[c][n];
          xv.x -= v[c].x*xs.x - v[c].y*xs.y;
          xv.y -= v[c].x*xs.y + v[c].y*xs.x;
          Xc[c][n] = xv;
        }
      }
    }
    // W update (single wave, lockstep read-then-write)
    if (tid < 16) {
      const int c = tid>>2, d = tid&3;
      float2 wsd = Wl[s][d];
      float2 wv = Wl[c][d];
      wv.x -= v[c].x*wsd.x - v[c].y*wsd.y;
      wv.y -= v[c].x*wsd.y + v[c].y*wsd.x;
      Wl[c][d] = wv;
    }
    __syncthreads();
  }

  // ---------- type-2 sweeps (taps from ORIGINAL input, delayed by 3-t) ----------
  for (int s=0;s<NC;s++) {
    const int ob = ((b*NC+s)*NF + f)*NFRM;
    for (int t2=0;t2<2;t2++) {
      float acc[12];
      #pragma unroll
      for (int i=0;i<12;i++) acc[i] = 0.f;
      float2 xt_c[KU_K];
      #pragma unroll
      for (int k=0;k<KU_K;k++) {
        int n = tid + k*KU_THREADS;
        if (n < NFRM) {
          float2 xt = make_float2(0.f, 0.f);
          int j = n + t2 - 3;
          if (j >= 0) xt = make_float2(Xor_[ob+j], Xoi_[ob+j]);
          xt_c[k] = xt;
          float m = xt.x*xt.x + xt.y*xt.y;
          #pragma unroll
          for (int c=0;c<NC;c++) {
            float2 xc = Xc[c][n];
            float w = w0g[c][k];
            acc[c]   += w*(xc.x*xt.x + xc.y*xt.y);
            acc[4+c] += w*(xc.y*xt.x - xc.x*xt.y);
            acc[8+c] += w*m;
          }
        }
      }
      #pragma unroll
      for (int o=32;o;o>>=1) {
        #pragma unroll
        for (int i=0;i<12;i++) acc[i] += __shfl_down(acc[i], o);
      }
      {
        const int lane = tid & 63, wid = tid >> 6;
        if (lane == 0) {
          #pragma unroll
          for (int i=0;i<12;i++) wpart[wid][i] = acc[i];
        }
      }
      __syncthreads();
      if (tid < 12) {
        float t = 0.f;
        #pragma unroll
        for (int w=0;w<8;w++) t += wpart[w][tid];
        vred[tid] = t;
      }
      __syncthreads();
      float2 v[NC];
      #pragma unroll
      for (int c=0;c<NC;c++) {
        float dn = fmaxf(vred[8+c]*norm, 1e-3f);
        v[c] = make_float2(vred[c]*norm/dn, vred[4+c]*norm/dn);
      }
      #pragma unroll
      for (int k=0;k<KU_K;k++) {
        int n = tid + k*KU_THREADS;
        if (n < NFRM) {
          float2 xt = xt_c[k];
          #pragma unroll
          for (int c=0;c<NC;c++) {
            float2 xv = Xc[c][n];
            xv.x -= v[c].x*xt.x - v[c].y*xt.y;
            xv.y -= v[c].x*xt.y + v[c].y*xt.x;
            Xc[c][n] = xv;
          }
        }
      }
      __syncthreads();
    }
  }

  // ---------- epilogue ----------
  if (LAST) {
    // projection_back: solve (W^T + 1e-6 I) a = e1, then Y = a[c] * X[c]
    if (tid == 0) {
      float2 A[4][4], bb[4], xv[4];
      for (int i=0;i<4;i++)
        for (int j=0;j<4;j++)
          A[i][j] = Wl[j][i];
      for (int i=0;i<4;i++) A[i][i].x += 1e-6f;
      bb[0] = make_float2(1.f,0.f);
      bb[1] = make_float2(0.f,0.f);
      bb[2] = make_float2(0.f,0.f);
      bb[3] = make_float2(0.f,0.f);
      for (int col=0; col<4; ++col) {
        int p = col;
        float best = A[col][col].x*A[col][col].x + A[col][col].y*A[col][col].y;
        for (int r=col+1;r<4;r++) {
          float m = A[r][col].x*A[r][col].x + A[r][col].y*A[r][col].y;
          if (m > best) { best = m; p = r; }
        }
        if (p != col) {
          for (int j=0;j<4;j++) { float2 ts = A[col][j]; A[col][j] = A[p][j]; A[p][j] = ts; }
          float2 ts = bb[col]; bb[col] = bb[p]; bb[p] = ts;
        }
        float2 piv = A[col][col];
        float ib = 1.0f / (piv.x*piv.x + piv.y*piv.y);
        float2 inv = make_float2(piv.x*ib, -piv.y*ib);
        for (int r=col+1;r<4;r++) {
          float2 fac = cmulf(A[r][col], inv);
          for (int j=col;j<4;j++) {
            float2 pr = cmulf(fac, A[col][j]);
            A[r][j].x -= pr.x; A[r][j].y -= pr.y;
          }
          float2 pb = cmulf(fac, bb[col]);
          bb[r].x -= pb.x; bb[r].y -= pb.y;
        }
      }
      for (int r=3;r>=0;r--) {
        float2 t = bb[r];
        for (int j=r+1;j<4;j++) {
          float2 pr = cmulf(A[r][j], xv[j]);
          t.x -= pr.x; t.y -= pr.y;
        }
        float2 d = A[r][r];
        float ib = 1.0f/(d.x*d.x + d.y*d.y);
        xv[r] = cmulf(t, make_float2(d.x*ib, -d.y*ib));
      }
      for (int c=0;c<4;c++) avec[c] = xv[c];
    }
    __syncthreads();
    #pragma unroll
    for (int c=0;c<NC;c++) {
      const int rb = ((b*NC+c)*NF + f)*NFRM;
      float2 a = avec[c];
      #pragma unroll
      for (int k=0;k<KU_K;k++) {
        int n = tid + k*KU_THREADS;
        if (n < NFRM) {
          float2 y = cmulf(a, Xc[c][n]);
          Xdr[rb+n] = y.x;   // real plane
          Xdi[rb+n] = y.y;   // imag plane
        }
      }
    }
  } else {
    #pragma unroll
    for (int c=0;c<NC;c++) {
      const int rb = ((b*NC+c)*NF + f)*NFRM;
      #pragma unroll
      for (int k=0;k<KU_K;k++) {
        int n = tid + k*KU_THREADS;
        if (n < NFRM) {
          float2 x = Xc[c][n];
          Xdr[rb+n] = x.x;
          Xdi[rb+n] = x.y;
        }
      }
    }
    if (tid < 16) Wg[(b*NF+f)*16 + tid] = Wl[tid>>2][tid&3];
  }
}

extern "C" void kernel_launch(void* const* d_in, const int* in_sizes, int n_in,
                              void* d_out, int out_size, void* d_ws, size_t ws_size,
                              hipStream_t stream)
{
  (void)in_sizes; (void)n_in; (void)out_size; (void)ws_size;
  const float* xr_in = (const float*)d_in[0];
  const float* xi_in = (const float*)d_in[1];
  float* outr = (float*)d_out;
  float* outi = outr + PLANE;

  char*  ws      = (char*)d_ws;
  float* partial = (float*)ws;                           // 4*4*4*2000 floats = 512,000 B
  float* gpart   = (float*)(ws + 512000);                // 48 floats (3 iters x 16)
  float2* Wg     = (float2*)(ws + 512000 + 256);         // 1028*16 float2 = 131,584 B

  dim3 grR(8, NFCH, NB*NC);   // 512 blocks
  dim3 grU(NF, NB);           // 1028 blocks

  k_zero<<<1, 64, 0, stream>>>(gpart);

  // iteration 0 (X = original input)
  k_r<<<grR, 256, 0, stream>>>(xr_in, xi_in, partial, gpart + 0);
  k_u<true,false><<<grU, KU_THREADS, 0, stream>>>(xr_in, xi_in, xr_in, xi_in,
                                                  outr, outi, partial, gpart + 0, Wg);
  // iteration 1
  k_r<<<grR, 256, 0, stream>>>(outr, outi, partial, gpart + 16);
  k_u<false,false><<<grU, KU_THREADS, 0, stream>>>(outr, outi, xr_in, xi_in,
                                                   outr, outi, partial, gpart + 16, Wg);
  // iteration 2 + projection_back (in-place, race-free: same addresses read/written per block)
  k_r<<<grR, 256, 0, stream>>>(outr, outi, partial, gpart + 32);
  k_u<false,true><<<grU, KU_THREADS, 0, stream>>>(outr, outi, xr_in, xi_in,
                                                  outr, outi, partial, gpart + 32, Wg);
}

// Round 2
// 696.315 us; speedup vs baseline: 1.1638x; 1.1638x over previous
//
#include <hip/hip_runtime.h>
#include <math.h>

// Problem constants (from reference)
#define NB   4
#define NC   4
#define NF   257
#define NFRM 2000
#define PLANE (NB*NC*NF*NFRM)   // 8,224,000
#define NFCH  8                 // frequency chunks for r-partials
#define FPERC 33                // ceil(257/8)
#define KU_THREADS 512
#define KU_K 4                  // frames per thread (4*512 >= 2000)

__device__ __forceinline__ float2 cmulf(float2 a, float2 b) {
  return make_float2(a.x*b.x - a.y*b.y, a.x*b.y + a.y*b.x);
}

__global__ __launch_bounds__(64)
void k_zero(float* __restrict__ gpart) {
  if (threadIdx.x < 48) gpart[threadIdx.x] = 0.f;
}

// r-pass: partial[bc][fc][n] = sum over f-chunk of |X[b,c,f,n]|^2  (float4 over n)
// and gpart[bc] += sum over (f,n) of |X|^2 (one atomic per block)
__global__ __launch_bounds__(256)
void k_r(const float* __restrict__ Xr, const float* __restrict__ Xi,
         float* __restrict__ partial, float* __restrict__ gpart)
{
  const int tid = threadIdx.x;
  const int q   = blockIdx.x*256 + tid;   // float4 index over n; 500 total
  const int fc  = blockIdx.y;
  const int bc  = blockIdx.z;             // b*4+c
  float4 s4 = make_float4(0.f,0.f,0.f,0.f);
  if (q < 500) {
    const int f0 = fc*FPERC;
    const int f1 = (f0+FPERC < NF) ? (f0+FPERC) : NF;
    const float4* r4 = (const float4*)(Xr + (size_t)(bc*NF+f0)*NFRM) + q;
    const float4* i4 = (const float4*)(Xi + (size_t)(bc*NF+f0)*NFRM) + q;
    for (int f=f0; f<f1; ++f) {
      float4 a = *r4, b2 = *i4;
      s4.x += a.x*a.x + b2.x*b2.x;
      s4.y += a.y*a.y + b2.y*b2.y;
      s4.z += a.z*a.z + b2.z*b2.z;
      s4.w += a.w*a.w + b2.w*b2.w;
      r4 += 500; i4 += 500;
    }
    ((float4*)(partial + (size_t)(bc*NFCH+fc)*NFRM))[q] = s4;
  }
  float t = s4.x+s4.y+s4.z+s4.w;
  #pragma unroll
  for (int o=32;o;o>>=1) t += __shfl_down(t, o);
  __shared__ float wred[4];
  if ((tid & 63) == 0) wred[tid>>6] = t;
  __syncthreads();
  if (tid == 0) atomicAdd(&gpart[bc], wred[0]+wred[1]+wred[2]+wred[3]);
}

// 12-value block reduction: in: acc[12] per thread; out: vred[12] in LDS. 2 barriers.
#define REDUCE12()                                                        \
  {                                                                       \
    _Pragma("unroll")                                                     \
    for (int o=32;o;o>>=1) {                                              \
      _Pragma("unroll")                                                   \
      for (int i=0;i<12;i++) acc[i] += __shfl_down(acc[i], o);            \
    }                                                                     \
    if ((tid & 63) == 0) {                                                \
      const int wid = tid >> 6;                                           \
      _Pragma("unroll")                                                   \
      for (int i=0;i<12;i++) wpart[wid][i] = acc[i];                      \
    }                                                                     \
    __syncthreads();                                                      \
    if (tid < 12) {                                                       \
      float t = 0.f;                                                      \
      _Pragma("unroll")                                                   \
      for (int w=0;w<8;w++) t += wpart[w][tid];                           \
      vred[tid] = t;                                                      \
    }                                                                     \
    __syncthreads();                                                      \
  }

// Per-(b,f) update kernel: X held entirely in REGISTERS (frame-local updates).
// LDS only for the 12-value cross-wave reduction + 4x4 W. 2 barriers/sweep.
template<bool FIRST, bool LAST>
__global__ __launch_bounds__(KU_THREADS, 4)
void k_u(const float* Xsr, const float* Xsi,                 // current X source planes
         const float* __restrict__ Xor_, const float* __restrict__ Xoi_, // ORIGINAL input (taps)
         float* Xdr, float* Xdi,                             // X dest planes (may alias source)
         const float* __restrict__ partial,
         const float* __restrict__ gpart,
         float2* __restrict__ Wg)
{
  __shared__ float wpart[8][12];
  __shared__ float vred[12];
  __shared__ float2 Wl[NC][NC];
  __shared__ float2 avec[NC];

  const int tid = threadIdx.x;
  const int f = blockIdx.x;
  const int b = blockIdx.y;
  const float norm = 1.0f/(float)NFRM;

  // g (per-channel gain) and 1/sqrt(g)
  float g[NC], igs[NC];
  #pragma unroll
  for (int c=0;c<NC;c++) {
    float m = gpart[b*NC+c] * (1.0f/(float)(NF*NFRM));
    g[c] = fmaxf(m, 1e-3f);
    igs[c] = 1.0f/sqrtf(g[c]);
  }

  // load + rescale X into registers (zero pad invalid frames)
  float2 x[NC][KU_K];
  #pragma unroll
  for (int c=0;c<NC;c++) {
    const size_t rb = ((size_t)(b*NC+c)*NF + f)*NFRM;
    #pragma unroll
    for (int k=0;k<KU_K;k++) {
      int n = tid + k*KU_THREADS;
      float2 xv = make_float2(0.f,0.f);
      if (n < NFRM) xv = make_float2(Xsr[rb+n]*igs[c], Xsi[rb+n]*igs[c]);
      x[c][k] = xv;
    }
  }
  // weights = w0[b,c,n] * g[c]   (w0 from pre-scale X via r-partials); 0 for invalid frames
  float w0g[NC][KU_K];
  #pragma unroll
  for (int k=0;k<KU_K;k++) {
    int n = tid + k*KU_THREADS;
    #pragma unroll
    for (int c=0;c<NC;c++) {
      float w = 0.f;
      if (n < NFRM) {
        const float* pp = partial + (size_t)(b*NC+c)*NFCH*NFRM + n;
        float r = 0.f;
        #pragma unroll
        for (int ch=0; ch<NFCH; ch++) r += pp[(size_t)ch*NFRM];
        w = 1.0f / fmaxf(2.0f*sqrtf(r), 1e-5f);
      }
      w0g[c][k] = w * g[c];
    }
  }
  // W load/init + rescale (wave 0 only; W is only ever touched by wave 0)
  if (tid < 16) {
    const int c = tid>>2, d = tid&3;
    float2 w;
    if (FIRST) w = make_float2((c==d)?1.f:0.f, 0.f);
    else       w = Wg[(size_t)(b*NF+f)*16 + tid];
    Wl[c][d] = make_float2(w.x*igs[c], w.y*igs[c]);
  }

  // ---------- type-1 sweeps (fully unrolled: all register indices static) ----------
  #pragma unroll
  for (int s=0;s<NC;s++) {
    float acc[12];
    #pragma unroll
    for (int i=0;i<12;i++) acc[i] = 0.f;
    #pragma unroll
    for (int k=0;k<KU_K;k++) {
      float2 xs = x[s][k];
      float m = xs.x*xs.x + xs.y*xs.y;
      #pragma unroll
      for (int c=0;c<NC;c++) {
        float2 xc = x[c][k];
        float w = w0g[c][k];
        acc[c]   += w*(xc.x*xs.x + xc.y*xs.y);   // Re  X[c]*conj(Xs)
        acc[4+c] += w*(xc.y*xs.x - xc.x*xs.y);   // Im
        acc[8+c] += w*m;                         // denom
      }
    }
    REDUCE12();
    float2 v[NC];
    #pragma unroll
    for (int c=0;c<NC;c++) {
      float dn = fmaxf(vred[8+c]*norm, 1e-3f);
      v[c] = make_float2(vred[c]*norm/dn, vred[4+c]*norm/dn);
    }
    v[s] = make_float2(1.0f - 1.0f/sqrtf(fmaxf(vred[8+s]*norm, 1e-3f)), 0.f);
    // X update — thread-private registers, NO barrier needed
    #pragma unroll
    for (int k=0;k<KU_K;k++) {
      float2 xs = x[s][k];   // snapshot before c==s update
      #pragma unroll
      for (int c=0;c<NC;c++) {
        float2 xv = x[c][k];
        xv.x -= v[c].x*xs.x - v[c].y*xs.y;
        xv.y -= v[c].x*xs.y + v[c].y*xs.x;
        x[c][k] = xv;
      }
    }
    // W update (wave 0, lockstep)
    if (tid < 16) {
      const int c = tid>>2, d = tid&3;
      float2 wsd = Wl[s][d];
      float2 wv = Wl[c][d];
      wv.x -= v[c].x*wsd.x - v[c].y*wsd.y;
      wv.y -= v[c].x*wsd.y + v[c].y*wsd.x;
      Wl[c][d] = wv;
    }
  }

  // ---------- type-2 sweeps (taps from ORIGINAL input, delay 3-t2) ----------
  #pragma unroll
  for (int s=0;s<NC;s++) {
    const size_t ob = ((size_t)(b*NC+s)*NF + f)*NFRM;
    #pragma unroll
    for (int t2=0;t2<2;t2++) {
      float2 xt[KU_K];
      #pragma unroll
      for (int k=0;k<KU_K;k++) {
        int n = tid + k*KU_THREADS;
        int j = n + t2 - 3;
        float2 tv = make_float2(0.f,0.f);
        if (n < NFRM && j >= 0) tv = make_float2(Xor_[ob+j], Xoi_[ob+j]);
        xt[k] = tv;
      }
      float acc[12];
      #pragma unroll
      for (int i=0;i<12;i++) acc[i] = 0.f;
      #pragma unroll
      for (int k=0;k<KU_K;k++) {
        float2 xs = xt[k];
        float m = xs.x*xs.x + xs.y*xs.y;
        #pragma unroll
        for (int c=0;c<NC;c++) {
          float2 xc = x[c][k];
          float w = w0g[c][k];
          acc[c]   += w*(xc.x*xs.x + xc.y*xs.y);
          acc[4+c] += w*(xc.y*xs.x - xc.x*xs.y);
          acc[8+c] += w*m;
        }
      }
      REDUCE12();
      float2 v[NC];
      #pragma unroll
      for (int c=0;c<NC;c++) {
        float dn = fmaxf(vred[8+c]*norm, 1e-3f);
        v[c] = make_float2(vred[c]*norm/dn, vred[4+c]*norm/dn);
      }
      #pragma unroll
      for (int k=0;k<KU_K;k++) {
        float2 xs = xt[k];
        #pragma unroll
        for (int c=0;c<NC;c++) {
          float2 xv = x[c][k];
          xv.x -= v[c].x*xs.x - v[c].y*xs.y;
          xv.y -= v[c].x*xs.y + v[c].y*xs.x;
          x[c][k] = xv;
        }
      }
    }
  }

  // ---------- epilogue ----------
  if (LAST) {
    // projection_back: solve (W^T + 1e-6 I) a = e1, then Y = a[c] * X[c]
    if (tid == 0) {
      float2 A[4][4], bb[4], xv[4];
      for (int i=0;i<4;i++)
        for (int j=0;j<4;j++)
          A[i][j] = Wl[j][i];
      for (int i=0;i<4;i++) A[i][i].x += 1e-6f;
      bb[0] = make_float2(1.f,0.f);
      bb[1] = make_float2(0.f,0.f);
      bb[2] = make_float2(0.f,0.f);
      bb[3] = make_float2(0.f,0.f);
      for (int col=0; col<4; ++col) {
        int p = col;
        float best = A[col][col].x*A[col][col].x + A[col][col].y*A[col][col].y;
        for (int r=col+1;r<4;r++) {
          float m = A[r][col].x*A[r][col].x + A[r][col].y*A[r][col].y;
          if (m > best) { best = m; p = r; }
        }
        if (p != col) {
          for (int j=0;j<4;j++) { float2 ts = A[col][j]; A[col][j] = A[p][j]; A[p][j] = ts; }
          float2 ts = bb[col]; bb[col] = bb[p]; bb[p] = ts;
        }
        float2 piv = A[col][col];
        float ib = 1.0f / (piv.x*piv.x + piv.y*piv.y);
        float2 inv = make_float2(piv.x*ib, -piv.y*ib);
        for (int r=col+1;r<4;r++) {
          float2 fac = cmulf(A[r][col], inv);
          for (int j=col;j<4;j++) {
            float2 pr = cmulf(fac, A[col][j]);
            A[r][j].x -= pr.x; A[r][j].y -= pr.y;
          }
          float2 pb = cmulf(fac, bb[col]);
          bb[r].x -= pb.x; bb[r].y -= pb.y;
        }
      }
      for (int r=3;r>=0;r--) {
        float2 t = bb[r];
        for (int j=r+1;j<4;j++) {
          float2 pr = cmulf(A[r][j], xv[j]);
          t.x -= pr.x; t.y -= pr.y;
        }
        float2 d = A[r][r];
        float ib = 1.0f/(d.x*d.x + d.y*d.y);
        xv[r] = cmulf(t, make_float2(d.x*ib, -d.y*ib));
      }
      for (int c=0;c<4;c++) avec[c] = xv[c];
    }
    __syncthreads();
    #pragma unroll
    for (int c=0;c<NC;c++) {
      const size_t rb = ((size_t)(b*NC+c)*NF + f)*NFRM;
      float2 a = avec[c];
      #pragma unroll
      for (int k=0;k<KU_K;k++) {
        int n = tid + k*KU_THREADS;
        if (n < NFRM) {
          float2 y = cmulf(a, x[c][k]);
          Xdr[rb+n] = y.x;   // real plane
          Xdi[rb+n] = y.y;   // imag plane
        }
      }
    }
  } else {
    #pragma unroll
    for (int c=0;c<NC;c++) {
      const size_t rb = ((size_t)(b*NC+c)*NF + f)*NFRM;
      #pragma unroll
      for (int k=0;k<KU_K;k++) {
        int n = tid + k*KU_THREADS;
        if (n < NFRM) {
          Xdr[rb+n] = x[c][k].x;
          Xdi[rb+n] = x[c][k].y;
        }
      }
    }
    if (tid < 16) Wg[(size_t)(b*NF+f)*16 + tid] = Wl[tid>>2][tid&3];
  }
}

extern "C" void kernel_launch(void* const* d_in, const int* in_sizes, int n_in,
                              void* d_out, int out_size, void* d_ws, size_t ws_size,
                              hipStream_t stream)
{
  (void)in_sizes; (void)n_in; (void)out_size; (void)ws_size;
  const float* xr_in = (const float*)d_in[0];
  const float* xi_in = (const float*)d_in[1];
  float* outr = (float*)d_out;
  float* outi = outr + PLANE;

  char*  ws      = (char*)d_ws;
  float* partial = (float*)ws;                             // 16*8*2000 floats = 1,024,000 B
  float* gpart   = (float*)(ws + 1024000);                 // 48 floats (3 iters x 16)
  float2* Wg     = (float2*)(ws + 1024000 + 256);          // 1028*16 float2 = 131,584 B

  dim3 grR(2, NFCH, NB*NC);   // 256 blocks
  dim3 grU(NF, NB);           // 1028 blocks

  k_zero<<<1, 64, 0, stream>>>(gpart);

  // iteration 0 (X = original input)
  k_r<<<grR, 256, 0, stream>>>(xr_in, xi_in, partial, gpart + 0);
  k_u<true,false><<<grU, KU_THREADS, 0, stream>>>(xr_in, xi_in, xr_in, xi_in,
                                                  outr, outi, partial, gpart + 0, Wg);
  // iteration 1
  k_r<<<grR, 256, 0, stream>>>(outr, outi, partial, gpart + 16);
  k_u<false,false><<<grU, KU_THREADS, 0, stream>>>(outr, outi, xr_in, xi_in,
                                                   outr, outi, partial, gpart + 16, Wg);
  // iteration 2 + projection_back (in-place, race-free: same addresses read/written per block)
  k_r<<<grR, 256, 0, stream>>>(outr, outi, partial, gpart + 32);
  k_u<false,true><<<grU, KU_THREADS, 0, stream>>>(outr, outi, xr_in, xi_in,
                                                  outr, outi, partial, gpart + 32, Wg);
}